// Round 6
// baseline (184.173 us; speedup 1.0000x reference)
//
#include <hip/hip_runtime.h>

typedef __attribute__((ext_vector_type(4))) float f32x4;
typedef __attribute__((ext_vector_type(8))) unsigned short u16x8;
typedef __attribute__((ext_vector_type(8))) __bf16 bf16x8;

typedef __attribute__((address_space(3))) unsigned lds_u32;
typedef const __attribute__((address_space(1))) unsigned glb_u32;

__device__ __forceinline__ unsigned short f2bf(float f) {
    union { float f; unsigned u; } v; v.f = f;
    unsigned r = v.u + 0x7fffu + ((v.u >> 16) & 1u);
    return (unsigned short)(r >> 16);
}

__device__ __forceinline__ f32x4 mfma16(u16x8 a, u16x8 b, f32x4 c) {
    return __builtin_amdgcn_mfma_f32_16x16x32_bf16(
        __builtin_bit_cast(bf16x8, a), __builtin_bit_cast(bf16x8, b), c, 0, 0, 0);
}

__device__ __forceinline__ void gload16(const unsigned short* g, unsigned short* l) {
    __builtin_amdgcn_global_load_lds((glb_u32*)g, (lds_u32*)l, 16, 0, 0);
}

// Minimum-fence sync set (m141 lesson: more walls = slower):
//  - barrier with memory clobber: orders all memory ops (ds/gload) across it,
//    but leaves VALU/MFMA free for the scheduler.
//  - lgkmcnt(0) + sched_barrier(0): required before register-MFMA (rule #18 —
//    MFMA is not a memory op, "memory" clobber alone doesn't order it).
//  - counted vmcnt with memory clobber only: its consumers are post-barrier
//    ds_reads (memory ops), so no sched wall needed.
#define BARM() asm volatile("s_barrier" ::: "memory")
#define WAITLGKM0() do { asm volatile("s_waitcnt lgkmcnt(0)" ::: "memory"); \
                         __builtin_amdgcn_sched_barrier(0); } while (0)
#define WAITVM6() asm volatile("s_waitcnt vmcnt(6)" ::: "memory")
#define WAITVM0() asm volatile("s_waitcnt vmcnt(0)" ::: "memory")

// ---------------- fp32 -> bf16 conversions ----------------
__global__ void cvt_f32_bf16(const float* __restrict__ src,
                             unsigned short* __restrict__ dst, int n) {
    int stride = gridDim.x * blockDim.x * 4;
    for (int i = (blockIdx.x * blockDim.x + threadIdx.x) * 4; i < n; i += stride) {
        float4 f = *reinterpret_cast<const float4*>(src + i);
        ushort4 o;
        o.x = f2bf(f.x); o.y = f2bf(f.y); o.z = f2bf(f.z); o.w = f2bf(f.w);
        *reinterpret_cast<ushort4*>(dst + i) = o;
    }
}

__global__ void cvt4_f32_bf16(const float* __restrict__ s0, const float* __restrict__ s1,
                              const float* __restrict__ s2, const float* __restrict__ s3,
                              unsigned short* __restrict__ dst, int per) {
    int total = per * 4;
    int stride = gridDim.x * blockDim.x * 4;
    for (int i = (blockIdx.x * blockDim.x + threadIdx.x) * 4; i < total; i += stride) {
        int w = i / per, off = i - w * per;
        const float* s = w == 0 ? s0 : w == 1 ? s1 : w == 2 ? s2 : s3;
        float4 f = *reinterpret_cast<const float4*>(s + off);
        ushort4 o;
        o.x = f2bf(f.x); o.y = f2bf(f.y); o.z = f2bf(f.z); o.w = f2bf(f.w);
        *reinterpret_cast<ushort4*>(dst + i) = o;
    }
}

// ---------------- 256x256 8-phase GEMM: C = A * B^T + bias ----------------
// A: M x K bf16 row-major.  B: N x K bf16 row-major.  K % 128 == 0.
// Output cols split every 768 into (C0,C1,C2), ldc=768.
// LDS map (bytes): A halves at  slot*32768 + half*16384        (64 KB)
//                  B halves at  65536 + slot*32768 + half*16384 (64 KB)
// Swizzle: logical (r, cb) of a [128][64bf16] half lives at phys r*128 + (cb ^ ((r&7)<<4)).
//
// WAR discipline (the round-2/3 bug): staging half h of A covers tile rows
// h*128..h*128+127, read by BOTH LDA8(slot,0) and LDA8(slot,1). So slot0-A
// restage at p4+ (last read p3), slot0-B at p3+ (last read p2), slot1-A at
// p8+ (last read p7), slot1-B at p7+ (last read p6).
template<bool OUTF32>
__global__ __launch_bounds__(512, 2) void gemm256(
    const unsigned short* __restrict__ A,
    const unsigned short* __restrict__ B,
    const float* __restrict__ b0, const float* __restrict__ b1, const float* __restrict__ b2,
    void* __restrict__ C0, void* __restrict__ C1, void* __restrict__ C2,
    int K, int NBY)
{
    __shared__ char lds[131072];
    const int t = threadIdx.x, lane = t & 63, wave = t >> 6;
    const int wm = wave >> 2, wn = wave & 3;   // 2 (M) x 4 (N) wave grid

    // XCD-aware bijective swizzle (nwg % 8 == 0 guaranteed by launch)
    const int nwg = gridDim.x;
    const int bid = blockIdx.x;
    const int swzb = (bid & 7) * (nwg >> 3) + (bid >> 3);
    const long m0 = (long)(swzb / NBY) * 256;
    const long n0 = (long)(swzb % NBY) * 256;

    const int NT = K >> 6;                      // K-tiles of 64 (even, >= 4)

    // staging geometry: thread t covers phys bytes t*16 (+ j*8192) of a half;
    // source col pre-swizzled so linear LDS + swizzled reads agree.
    const int rloc = t >> 3;                                  // row 0..63 per issue
    const int cel  = ((t & 7) ^ ((t >> 3) & 7)) << 3;         // src col element
    const unsigned short* Abase = A + (m0 + rloc) * (long)K + cel;
    const unsigned short* Bbase = B + (n0 + rloc) * (long)K + cel;

    auto STAGEA = [&](int kt, int h) {
        char* dst = lds + ((kt & 1) << 15) + (h << 14) + (wave << 10);
        const unsigned short* src = Abase + (long)(h * 128) * K + kt * 64;
        gload16(src, (unsigned short*)dst);
        gload16(src + (long)64 * K, (unsigned short*)(dst + 8192));
    };
    auto STAGEB = [&](int kt, int h) {
        char* dst = lds + 65536 + ((kt & 1) << 15) + (h << 14) + (wave << 10);
        const unsigned short* src = Bbase + (long)(h * 128) * K + kt * 64;
        gload16(src, (unsigned short*)dst);
        gload16(src + (long)64 * K, (unsigned short*)(dst + 8192));
    };

    f32x4 acc[8][4] = {};
    u16x8 a[4][2], bl0[2][2], bl1[2][2];

    auto LDA8 = [&](int slot, int mh) {
        const char* buf = lds + (slot << 15) + (wm << 14);
        #pragma unroll
        for (int mi = 0; mi < 4; ++mi)
            #pragma unroll
            for (int kk = 0; kk < 2; ++kk) {
                int r = mh * 64 + mi * 16 + (lane & 15);
                int cb = kk * 64 + (lane >> 4) * 16;
                a[mi][kk] = *(const u16x8*)(buf + r * 128 + (cb ^ ((r & 7) << 4)));
            }
    };
    auto LDB4 = [&](int slot, int nh, u16x8 bf[2][2]) {
        const char* buf = lds + 65536 + (slot << 15) + ((wn >> 1) << 14);
        #pragma unroll
        for (int ni = 0; ni < 2; ++ni)
            #pragma unroll
            for (int kk = 0; kk < 2; ++kk) {
                int r = (wn & 1) * 64 + nh * 32 + ni * 16 + (lane & 15);
                int cb = kk * 64 + (lane >> 4) * 16;
                bf[ni][kk] = *(const u16x8*)(buf + r * 128 + (cb ^ ((r & 7) << 4)));
            }
    };
    auto MF16 = [&](int mh, int nh, u16x8 bf[2][2]) {
        __builtin_amdgcn_s_setprio(1);
        #pragma unroll
        for (int mi = 0; mi < 4; ++mi)
            #pragma unroll
            for (int ni = 0; ni < 2; ++ni)
                #pragma unroll
                for (int kk = 0; kk < 2; ++kk)
                    acc[mh * 4 + mi][nh * 2 + ni] =
                        mfma16(a[mi][kk], bf[ni][kk], acc[mh * 4 + mi][nh * 2 + ni]);
        __builtin_amdgcn_s_setprio(0);
    };

    // ---- prologue: tile 0 complete + 3 halves of tile 1, then FULL drain ----
    // (drain makes prologue issue order irrelevant to the loop's vmcnt ledger)
    STAGEA(0, 0); STAGEB(0, 0); STAGEB(0, 1); STAGEA(0, 1);
    STAGEA(1, 0); STAGEB(1, 0); STAGEB(1, 1);
    WAITVM0();
    BARM();

    // ---- main loop: 8 phases / 2 K-tiles per iteration ----
    // vmcnt ledger (2 loads per STAGE). Steady state: enter p1 with 6
    // outstanding = tb's {B0, A0, B1} from prev p7/p8.
    //   p1 +A(tb,1)=8 | p3 +B(t2,0)=10 | p4 +A(t2,0)+B(t2,1)=14
    //     -> vmcnt(6) drains oldest 8 = tile tb complete before p5 reads it.
    //   p5 +A(t2,1)=8 | p7 +B(t3,0)=10 | p8 +A(t3,0)+B(t3,1)=14
    //     -> vmcnt(6) drains oldest 8 = tile t2 complete before next p1.
    for (int I = 0; I < (NT >> 1); ++I) {
        const int tb = 2 * I + 1;
        int t2 = 2 * I + 2; if (t2 >= NT) t2 -= 2;   // redirect: same slot, identical bytes
        int t3 = 2 * I + 3; if (t3 >= NT) t3 -= 2;

        // p1
        LDA8(0, 0); LDB4(0, 0, bl0); STAGEA(tb, 1);
        BARM(); WAITLGKM0();
        MF16(0, 0, bl0); BARM();
        // p2  (no stage: slot0-A still live until p3)
        LDB4(0, 1, bl1);
        BARM(); WAITLGKM0();
        MF16(0, 1, bl1); BARM();
        // p3
        LDA8(0, 1); STAGEB(t2, 0);
        BARM(); WAITLGKM0();
        MF16(1, 1, bl1); BARM();
        // p4  (slot0-A reads done at p3 -> safe to restage)
        STAGEA(t2, 0); STAGEB(t2, 1);
        WAITVM6(); BARM();
        MF16(1, 0, bl0); BARM();
        // p5
        LDA8(1, 0); LDB4(1, 0, bl0); STAGEA(t2, 1);
        BARM(); WAITLGKM0();
        MF16(0, 0, bl0); BARM();
        // p6  (no stage: slot1-A still live until p7)
        LDB4(1, 1, bl1);
        BARM(); WAITLGKM0();
        MF16(0, 1, bl1); BARM();
        // p7
        LDA8(1, 1); STAGEB(t3, 0);
        BARM(); WAITLGKM0();
        MF16(1, 1, bl1); BARM();
        // p8  (slot1-A reads done at p7 -> safe to restage)
        STAGEA(t3, 0); STAGEB(t3, 1);
        WAITVM6(); BARM();
        MF16(1, 0, bl0); BARM();
    }

    // ---- epilogue: C/D layout col=lane&15, row=(lane>>4)*4+reg ----
    #pragma unroll
    for (int mh = 0; mh < 2; ++mh)
        #pragma unroll
        for (int mi = 0; mi < 4; ++mi)
            #pragma unroll
            for (int nf = 0; nf < 4; ++nf) {
                int coln = (int)n0 + wn * 64 + nf * 16 + (lane & 15);
                int which = coln / 768;
                int nl = coln - which * 768;
                const float* bs = which == 0 ? b0 : (which == 1 ? b1 : b2);
                void* Cp       = which == 0 ? C0 : (which == 1 ? C1 : C2);
                float bias = bs[nl];
                #pragma unroll
                for (int q = 0; q < 4; ++q) {
                    long row = m0 + wm * 128 + mh * 64 + mi * 16 + ((lane >> 4) << 2) + q;
                    float val = acc[mh * 4 + mi][nf][q] + bias;
                    if (OUTF32) ((float*)Cp)[row * 768 + nl] = val;
                    else ((unsigned short*)Cp)[row * 768 + nl] = f2bf(val);
                }
            }
}

// ---------------- axial attention, seq len 128, head_dim 64 ----------------
__global__ __launch_bounds__(256, 3) void attn128(
    const unsigned short* __restrict__ Q,
    const unsigned short* __restrict__ K,
    const unsigned short* __restrict__ V,
    unsigned short* __restrict__ O,
    int mult, int stride)
{
    __shared__ unsigned short QK[2][128][72];
    __shared__ unsigned short Vst[64][136];
    unsigned short (*Qs)[72] = QK[0];
    unsigned short (*Ks)[72] = QK[1];
    unsigned short (*Ps)[136] = (unsigned short (*)[136])&QK[0][0][0];

    const int pos = blockIdx.x, head = blockIdx.y;
    const int t = threadIdx.x, wave = t >> 6, lane = t & 63;

    for (int p = 0; p < 4; ++p) {
        int f = p * 2048 + t * 8;
        int r = f >> 6;
        int d = f & 63;
        long g = ((long)(pos * mult + r * stride)) * 768 + head * 64 + d;
        *(u16x8*)&Qs[r][d] = *(const u16x8*)&Q[g];
        *(u16x8*)&Ks[r][d] = *(const u16x8*)&K[g];
        u16x8 vv = *(const u16x8*)&V[g];
        #pragma unroll
        for (int j = 0; j < 8; ++j) Vst[d + j][r] = vv[j];
    }
    __syncthreads();

    const int rb = wave * 32;
    f32x4 s[2][8] = {};
    #pragma unroll
    for (int d0 = 0; d0 < 64; d0 += 32) {
        u16x8 a[2], b[8];
        #pragma unroll
        for (int mi = 0; mi < 2; ++mi)
            a[mi] = *(const u16x8*)&Qs[rb + mi * 16 + (lane & 15)][d0 + (lane >> 4) * 8];
        #pragma unroll
        for (int ni = 0; ni < 8; ++ni)
            b[ni] = *(const u16x8*)&Ks[ni * 16 + (lane & 15)][d0 + (lane >> 4) * 8];
        #pragma unroll
        for (int mi = 0; mi < 2; ++mi)
            #pragma unroll
            for (int ni = 0; ni < 8; ++ni)
                s[mi][ni] = mfma16(a[mi], b[ni], s[mi][ni]);
    }
    __syncthreads();

    #pragma unroll
    for (int mi = 0; mi < 2; ++mi) {
        #pragma unroll
        for (int q = 0; q < 4; ++q) {
            float m = -1e30f;
            #pragma unroll
            for (int ni = 0; ni < 8; ++ni) m = fmaxf(m, s[mi][ni][q]);
            m = fmaxf(m, __shfl_xor(m, 1));
            m = fmaxf(m, __shfl_xor(m, 2));
            m = fmaxf(m, __shfl_xor(m, 4));
            m = fmaxf(m, __shfl_xor(m, 8));
            float p[8], sum = 0.f;
            #pragma unroll
            for (int ni = 0; ni < 8; ++ni) { p[ni] = __expf(s[mi][ni][q] - m); sum += p[ni]; }
            sum += __shfl_xor(sum, 1);
            sum += __shfl_xor(sum, 2);
            sum += __shfl_xor(sum, 4);
            sum += __shfl_xor(sum, 8);
            float inv = 1.0f / sum;
            int row = rb + mi * 16 + ((lane >> 4) << 2) + q;
            #pragma unroll
            for (int ni = 0; ni < 8; ++ni)
                Ps[row][ni * 16 + (lane & 15)] = f2bf(p[ni] * inv);
        }
    }
    __syncthreads();

    f32x4 o[2][4] = {};
    #pragma unroll
    for (int v0 = 0; v0 < 128; v0 += 32) {
        u16x8 a[2], b[4];
        #pragma unroll
        for (int mi = 0; mi < 2; ++mi)
            a[mi] = *(const u16x8*)&Ps[rb + mi * 16 + (lane & 15)][v0 + (lane >> 4) * 8];
        #pragma unroll
        for (int ni = 0; ni < 4; ++ni)
            b[ni] = *(const u16x8*)&Vst[ni * 16 + (lane & 15)][v0 + (lane >> 4) * 8];
        #pragma unroll
        for (int mi = 0; mi < 2; ++mi)
            #pragma unroll
            for (int ni = 0; ni < 4; ++ni)
                o[mi][ni] = mfma16(a[mi], b[ni], o[mi][ni]);
    }

    #pragma unroll
    for (int mi = 0; mi < 2; ++mi)
        #pragma unroll
        for (int ni = 0; ni < 4; ++ni)
            #pragma unroll
            for (int q = 0; q < 4; ++q) {
                int row = rb + mi * 16 + ((lane >> 4) << 2) + q;
                int col = ni * 16 + (lane & 15);
                long g = ((long)(pos * mult + row * stride)) * 768 + head * 64 + col;
                O[g] = f2bf(o[mi][ni][q]);
            }
}

extern "C" void kernel_launch(void* const* d_in, const int* in_sizes, int n_in,
                              void* d_out, int out_size, void* d_ws, size_t ws_size,
                              hipStream_t stream) {
    const float* x  = (const float*)d_in[0];
    const float* Wq = (const float*)d_in[1];
    const float* bq = (const float*)d_in[2];
    const float* Wk = (const float*)d_in[3];
    const float* bk = (const float*)d_in[4];
    const float* Wv = (const float*)d_in[5];
    const float* bv = (const float*)d_in[6];
    const float* Wo = (const float*)d_in[7];
    const float* bo = (const float*)d_in[8];
    float* out = (float*)d_out;

    const size_t MS = (size_t)16384 * 768;
    const size_t WS = (size_t)768 * 768;
    unsigned short* xb   = (unsigned short*)d_ws;   // later reused as O1
    unsigned short* Qb   = xb + MS;
    unsigned short* Kb   = Qb + MS;
    unsigned short* Vb   = Kb + MS;                 // later reused as O2
    unsigned short* Wqkv = Vb + MS;
    unsigned short* Wob  = Wqkv + 3 * WS;

    cvt_f32_bf16<<<2048, 256, 0, stream>>>(x, xb, (int)MS);
    cvt4_f32_bf16<<<2304, 256, 0, stream>>>(Wq, Wk, Wv, Wo, Wqkv, (int)WS);

    // QKV projection: M=16384, N=2304 (Q|K|V), K=768. 64x9 = 576 blocks.
    gemm256<false><<<576, 512, 0, stream>>>(
        xb, Wqkv, bq, bk, bv, Qb, Kb, Vb, 768, 9);

    // width attention. O1 -> xb
    attn128<<<dim3(128, 12), 256, 0, stream>>>(Qb, Kb, Vb, xb, 128, 1);
    // height attention: V-input = O1 (xb). O2 -> Vb
    attn128<<<dim3(128, 12), 256, 0, stream>>>(Qb, Kb, xb, Vb, 1, 128);

    // output projection: M=16384, N=768, K=768, fp32 out. 64x3 = 192 blocks.
    gemm256<true><<<192, 512, 0, stream>>>(
        Vb, Wob, bo, bo, bo, out, out, out, 768, 3);
}

// Round 7
// 180.693 us; speedup vs baseline: 1.0193x; 1.0193x over previous
//
#include <hip/hip_runtime.h>

typedef __attribute__((ext_vector_type(4))) float f32x4;
typedef __attribute__((ext_vector_type(8))) unsigned short u16x8;
typedef __attribute__((ext_vector_type(8))) __bf16 bf16x8;

typedef __attribute__((address_space(3))) unsigned lds_u32;
typedef const __attribute__((address_space(1))) unsigned glb_u32;

__device__ __forceinline__ unsigned short f2bf(float f) {
    union { float f; unsigned u; } v; v.f = f;
    unsigned r = v.u + 0x7fffu + ((v.u >> 16) & 1u);
    return (unsigned short)(r >> 16);
}

__device__ __forceinline__ f32x4 mfma16(u16x8 a, u16x8 b, f32x4 c) {
    return __builtin_amdgcn_mfma_f32_16x16x32_bf16(
        __builtin_bit_cast(bf16x8, a), __builtin_bit_cast(bf16x8, b), c, 0, 0, 0);
}

__device__ __forceinline__ void gload16(const unsigned short* g, unsigned short* l) {
    __builtin_amdgcn_global_load_lds((glb_u32*)g, (lds_u32*)l, 16, 0, 0);
}

// barrier with memory clobber: orders ds/gload memory ops across it, leaves
// VALU/MFMA scheduling free; compiler tracks ds_read->MFMA deps itself with
// fine-grained lgkmcnt(N) (no hard walls -- R5/m141 lesson).
#define BARM() asm volatile("s_barrier" ::: "memory")
#define WAITVM6() asm volatile("s_waitcnt vmcnt(6)" ::: "memory")
#define WAITVM0() asm volatile("s_waitcnt vmcnt(0)" ::: "memory")

// ---------------- fp32 -> bf16 conversions ----------------
__global__ void cvt_f32_bf16(const float* __restrict__ src,
                             unsigned short* __restrict__ dst, int n) {
    int stride = gridDim.x * blockDim.x * 4;
    for (int i = (blockIdx.x * blockDim.x + threadIdx.x) * 4; i < n; i += stride) {
        float4 f = *reinterpret_cast<const float4*>(src + i);
        ushort4 o;
        o.x = f2bf(f.x); o.y = f2bf(f.y); o.z = f2bf(f.z); o.w = f2bf(f.w);
        *reinterpret_cast<ushort4*>(dst + i) = o;
    }
}

__global__ void cvt4_f32_bf16(const float* __restrict__ s0, const float* __restrict__ s1,
                              const float* __restrict__ s2, const float* __restrict__ s3,
                              unsigned short* __restrict__ dst, int per) {
    int total = per * 4;
    int stride = gridDim.x * blockDim.x * 4;
    for (int i = (blockIdx.x * blockDim.x + threadIdx.x) * 4; i < total; i += stride) {
        int w = i / per, off = i - w * per;
        const float* s = w == 0 ? s0 : w == 1 ? s1 : w == 2 ? s2 : s3;
        float4 f = *reinterpret_cast<const float4*>(s + off);
        ushort4 o;
        o.x = f2bf(f.x); o.y = f2bf(f.y); o.z = f2bf(f.z); o.w = f2bf(f.w);
        *reinterpret_cast<ushort4*>(dst + i) = o;
    }
}

// ---------------- 256x256 8-phase GEMM: C = A * B^T + bias ----------------
// A: M x K bf16 row-major.  B: N x K bf16 row-major.  K % 128 == 0.
// Output cols split every 768 into (C0,C1,C2), ldc=768.
// LDS map (bytes): A halves at  slot*32768 + half*16384        (64 KB)
//                  B halves at  65536 + slot*32768 + half*16384 (64 KB)
// Swizzle: logical (r, cb) of a [128][64bf16] half lives at phys r*128 + (cb ^ ((r&7)<<4)).
//
// 1-barrier phase layout: [ds reads; BARRIER; stage issue; MFMA].
//   WAR: stage(pX) issues post-barrier(pX); every wave's reads through pX
//        precede that barrier -> stage safe if last read of its target <= pX.
//        Placements: slot0-B@p3 (last read p2), slot0-A@p4 (p3),
//                    slot1-B@p7 (p6), slot1-A@p8 (p7). All satisfied.
//   RAW: staged-tile completion = vmcnt(6) -> barrier -> reads, so p4/p8
//        carry a second barrier after the vmcnt.
template<bool OUTF32>
__global__ __launch_bounds__(512, 2) void gemm256(
    const unsigned short* __restrict__ A,
    const unsigned short* __restrict__ B,
    const float* __restrict__ b0, const float* __restrict__ b1, const float* __restrict__ b2,
    void* __restrict__ C0, void* __restrict__ C1, void* __restrict__ C2,
    int K, int NBY)
{
    __shared__ char lds[131072];
    const int t = threadIdx.x, lane = t & 63, wave = t >> 6;
    const int wm = wave >> 2, wn = wave & 3;   // 2 (M) x 4 (N) wave grid

    // XCD-aware bijective swizzle (nwg % 8 == 0 guaranteed by launch)
    const int nwg = gridDim.x;
    const int bid = blockIdx.x;
    const int swzb = (bid & 7) * (nwg >> 3) + (bid >> 3);
    const long m0 = (long)(swzb / NBY) * 256;
    const long n0 = (long)(swzb % NBY) * 256;

    const int NT = K >> 6;                      // K-tiles of 64 (even, >= 4)

    // staging geometry: thread t covers phys bytes t*16 (+ j*8192) of a half;
    // source col pre-swizzled so linear LDS + swizzled reads agree.
    const int rloc = t >> 3;                                  // row 0..63 per issue
    const int cel  = ((t & 7) ^ ((t >> 3) & 7)) << 3;         // src col element
    const unsigned short* Abase = A + (m0 + rloc) * (long)K + cel;
    const unsigned short* Bbase = B + (n0 + rloc) * (long)K + cel;

    auto STAGEA = [&](int kt, int h) {
        char* dst = lds + ((kt & 1) << 15) + (h << 14) + (wave << 10);
        const unsigned short* src = Abase + (long)(h * 128) * K + kt * 64;
        gload16(src, (unsigned short*)dst);
        gload16(src + (long)64 * K, (unsigned short*)(dst + 8192));
    };
    auto STAGEB = [&](int kt, int h) {
        char* dst = lds + 65536 + ((kt & 1) << 15) + (h << 14) + (wave << 10);
        const unsigned short* src = Bbase + (long)(h * 128) * K + kt * 64;
        gload16(src, (unsigned short*)dst);
        gload16(src + (long)64 * K, (unsigned short*)(dst + 8192));
    };

    f32x4 acc[8][4] = {};
    u16x8 a[4][2], bl0[2][2], bl1[2][2];

    auto LDA8 = [&](int slot, int mh) {
        const char* buf = lds + (slot << 15) + (wm << 14);
        #pragma unroll
        for (int mi = 0; mi < 4; ++mi)
            #pragma unroll
            for (int kk = 0; kk < 2; ++kk) {
                int r = mh * 64 + mi * 16 + (lane & 15);
                int cb = kk * 64 + (lane >> 4) * 16;
                a[mi][kk] = *(const u16x8*)(buf + r * 128 + (cb ^ ((r & 7) << 4)));
            }
    };
    auto LDB4 = [&](int slot, int nh, u16x8 bf[2][2]) {
        const char* buf = lds + 65536 + (slot << 15) + ((wn >> 1) << 14);
        #pragma unroll
        for (int ni = 0; ni < 2; ++ni)
            #pragma unroll
            for (int kk = 0; kk < 2; ++kk) {
                int r = (wn & 1) * 64 + nh * 32 + ni * 16 + (lane & 15);
                int cb = kk * 64 + (lane >> 4) * 16;
                bf[ni][kk] = *(const u16x8*)(buf + r * 128 + (cb ^ ((r & 7) << 4)));
            }
    };
    auto MF16 = [&](int mh, int nh, u16x8 bf[2][2]) {
        __builtin_amdgcn_s_setprio(1);
        #pragma unroll
        for (int mi = 0; mi < 4; ++mi)
            #pragma unroll
            for (int ni = 0; ni < 2; ++ni)
                #pragma unroll
                for (int kk = 0; kk < 2; ++kk)
                    acc[mh * 4 + mi][nh * 2 + ni] =
                        mfma16(a[mi][kk], bf[ni][kk], acc[mh * 4 + mi][nh * 2 + ni]);
        __builtin_amdgcn_s_setprio(0);
    };

    // ---- prologue: tile 0 complete + 3 halves of tile 1, then FULL drain ----
    STAGEA(0, 0); STAGEB(0, 0); STAGEB(0, 1); STAGEA(0, 1);
    STAGEA(1, 0); STAGEB(1, 0); STAGEB(1, 1);
    WAITVM0();
    BARM();

    // ---- main loop: 8 phases / 2 K-tiles per iteration ----
    // vmcnt ledger (2 loads per STAGE). Steady: enter p1 with 6 outstanding
    // (tb's B0@p7, A0+B1@p8 of prev iter).
    //   p1 +A(tb,1)=8 | p3 +B(t2,0)=10 | p4 +A(t2,0)+B(t2,1)=14
    //     -> vmcnt(6): tile tb complete; barrier; p5+ reads slot1 safely.
    //   p5 +A(t2,1)=8 | p7 +B(t3,0)=10 | p8 +A(t3,0)+B(t3,1)=14
    //     -> vmcnt(6): tile t2 complete; barrier; next-p1 reads slot0 safely.
    for (int I = 0; I < (NT >> 1); ++I) {
        const int tb = 2 * I + 1;
        int t2 = 2 * I + 2; if (t2 >= NT) t2 -= 2;   // redirect: same slot, identical bytes
        int t3 = 2 * I + 3; if (t3 >= NT) t3 -= 2;

        // p1
        LDA8(0, 0); LDB4(0, 0, bl0);
        BARM();
        STAGEA(tb, 1);
        MF16(0, 0, bl0);
        // p2
        LDB4(0, 1, bl1);
        BARM();
        MF16(0, 1, bl1);
        // p3
        LDA8(0, 1);
        BARM();
        STAGEB(t2, 0);
        MF16(1, 1, bl1);
        // p4  (no reads; double-barrier around the counted drain)
        STAGEA(t2, 0); STAGEB(t2, 1);
        WAITVM6();
        BARM();
        MF16(1, 0, bl0);
        BARM();
        // p5
        LDA8(1, 0); LDB4(1, 0, bl0);
        BARM();
        STAGEA(t2, 1);
        MF16(0, 0, bl0);
        // p6
        LDB4(1, 1, bl1);
        BARM();
        MF16(0, 1, bl1);
        // p7
        LDA8(1, 1);
        BARM();
        STAGEB(t3, 0);
        MF16(1, 1, bl1);
        // p8
        STAGEA(t3, 0); STAGEB(t3, 1);
        WAITVM6();
        BARM();
        MF16(1, 0, bl0);
        BARM();
    }

    // ---- epilogue: C/D layout col=lane&15, row=(lane>>4)*4+reg ----
    #pragma unroll
    for (int mh = 0; mh < 2; ++mh)
        #pragma unroll
        for (int mi = 0; mi < 4; ++mi)
            #pragma unroll
            for (int nf = 0; nf < 4; ++nf) {
                int coln = (int)n0 + wn * 64 + nf * 16 + (lane & 15);
                int which = coln / 768;
                int nl = coln - which * 768;
                const float* bs = which == 0 ? b0 : (which == 1 ? b1 : b2);
                void* Cp       = which == 0 ? C0 : (which == 1 ? C1 : C2);
                float bias = bs[nl];
                #pragma unroll
                for (int q = 0; q < 4; ++q) {
                    long row = m0 + wm * 128 + mh * 64 + mi * 16 + ((lane >> 4) << 2) + q;
                    float val = acc[mh * 4 + mi][nf][q] + bias;
                    if (OUTF32) ((float*)Cp)[row * 768 + nl] = val;
                    else ((unsigned short*)Cp)[row * 768 + nl] = f2bf(val);
                }
            }
}

// ---------------- axial attention, seq len 128, head_dim 64 ----------------
__global__ __launch_bounds__(256, 3) void attn128(
    const unsigned short* __restrict__ Q,
    const unsigned short* __restrict__ K,
    const unsigned short* __restrict__ V,
    unsigned short* __restrict__ O,
    int mult, int stride)
{
    __shared__ unsigned short QK[2][128][72];
    __shared__ unsigned short Vst[64][136];
    unsigned short (*Qs)[72] = QK[0];
    unsigned short (*Ks)[72] = QK[1];
    unsigned short (*Ps)[136] = (unsigned short (*)[136])&QK[0][0][0];

    const int pos = blockIdx.x, head = blockIdx.y;
    const int t = threadIdx.x, wave = t >> 6, lane = t & 63;

    for (int p = 0; p < 4; ++p) {
        int f = p * 2048 + t * 8;
        int r = f >> 6;
        int d = f & 63;
        long g = ((long)(pos * mult + r * stride)) * 768 + head * 64 + d;
        *(u16x8*)&Qs[r][d] = *(const u16x8*)&Q[g];
        *(u16x8*)&Ks[r][d] = *(const u16x8*)&K[g];
        u16x8 vv = *(const u16x8*)&V[g];
        #pragma unroll
        for (int j = 0; j < 8; ++j) Vst[d + j][r] = vv[j];
    }
    __syncthreads();

    const int rb = wave * 32;
    f32x4 s[2][8] = {};
    #pragma unroll
    for (int d0 = 0; d0 < 64; d0 += 32) {
        u16x8 a[2], b[8];
        #pragma unroll
        for (int mi = 0; mi < 2; ++mi)
            a[mi] = *(const u16x8*)&Qs[rb + mi * 16 + (lane & 15)][d0 + (lane >> 4) * 8];
        #pragma unroll
        for (int ni = 0; ni < 8; ++ni)
            b[ni] = *(const u16x8*)&Ks[ni * 16 + (lane & 15)][d0 + (lane >> 4) * 8];
        #pragma unroll
        for (int mi = 0; mi < 2; ++mi)
            #pragma unroll
            for (int ni = 0; ni < 8; ++ni)
                s[mi][ni] = mfma16(a[mi], b[ni], s[mi][ni]);
    }
    __syncthreads();

    #pragma unroll
    for (int mi = 0; mi < 2; ++mi) {
        #pragma unroll
        for (int q = 0; q < 4; ++q) {
            float m = -1e30f;
            #pragma unroll
            for (int ni = 0; ni < 8; ++ni) m = fmaxf(m, s[mi][ni][q]);
            m = fmaxf(m, __shfl_xor(m, 1));
            m = fmaxf(m, __shfl_xor(m, 2));
            m = fmaxf(m, __shfl_xor(m, 4));
            m = fmaxf(m, __shfl_xor(m, 8));
            float p[8], sum = 0.f;
            #pragma unroll
            for (int ni = 0; ni < 8; ++ni) { p[ni] = __expf(s[mi][ni][q] - m); sum += p[ni]; }
            sum += __shfl_xor(sum, 1);
            sum += __shfl_xor(sum, 2);
            sum += __shfl_xor(sum, 4);
            sum += __shfl_xor(sum, 8);
            float inv = 1.0f / sum;
            int row = rb + mi * 16 + ((lane >> 4) << 2) + q;
            #pragma unroll
            for (int ni = 0; ni < 8; ++ni)
                Ps[row][ni * 16 + (lane & 15)] = f2bf(p[ni] * inv);
        }
    }
    __syncthreads();

    f32x4 o[2][4] = {};
    #pragma unroll
    for (int v0 = 0; v0 < 128; v0 += 32) {
        u16x8 a[2], b[4];
        #pragma unroll
        for (int mi = 0; mi < 2; ++mi)
            a[mi] = *(const u16x8*)&Ps[rb + mi * 16 + (lane & 15)][v0 + (lane >> 4) * 8];
        #pragma unroll
        for (int ni = 0; ni < 4; ++ni)
            b[ni] = *(const u16x8*)&Vst[ni * 16 + (lane & 15)][v0 + (lane >> 4) * 8];
        #pragma unroll
        for (int mi = 0; mi < 2; ++mi)
            #pragma unroll
            for (int ni = 0; ni < 4; ++ni)
                o[mi][ni] = mfma16(a[mi], b[ni], o[mi][ni]);
    }

    #pragma unroll
    for (int mi = 0; mi < 2; ++mi)
        #pragma unroll
        for (int ni = 0; ni < 4; ++ni)
            #pragma unroll
            for (int q = 0; q < 4; ++q) {
                int row = rb + mi * 16 + ((lane >> 4) << 2) + q;
                int col = ni * 16 + (lane & 15);
                long g = ((long)(pos * mult + row * stride)) * 768 + head * 64 + col;
                O[g] = f2bf(o[mi][ni][q]);
            }
}

extern "C" void kernel_launch(void* const* d_in, const int* in_sizes, int n_in,
                              void* d_out, int out_size, void* d_ws, size_t ws_size,
                              hipStream_t stream) {
    const float* x  = (const float*)d_in[0];
    const float* Wq = (const float*)d_in[1];
    const float* bq = (const float*)d_in[2];
    const float* Wk = (const float*)d_in[3];
    const float* bk = (const float*)d_in[4];
    const float* Wv = (const float*)d_in[5];
    const float* bv = (const float*)d_in[6];
    const float* Wo = (const float*)d_in[7];
    const float* bo = (const float*)d_in[8];
    float* out = (float*)d_out;

    const size_t MS = (size_t)16384 * 768;
    const size_t WS = (size_t)768 * 768;
    unsigned short* xb   = (unsigned short*)d_ws;   // later reused as O1
    unsigned short* Qb   = xb + MS;
    unsigned short* Kb   = Qb + MS;
    unsigned short* Vb   = Kb + MS;                 // later reused as O2
    unsigned short* Wqkv = Vb + MS;
    unsigned short* Wob  = Wqkv + 3 * WS;

    cvt_f32_bf16<<<2048, 256, 0, stream>>>(x, xb, (int)MS);
    cvt4_f32_bf16<<<2304, 256, 0, stream>>>(Wq, Wk, Wv, Wo, Wqkv, (int)WS);

    // QKV projection: M=16384, N=2304 (Q|K|V), K=768. 64x9 = 576 blocks.
    gemm256<false><<<576, 512, 0, stream>>>(
        xb, Wqkv, bq, bk, bv, Qb, Kb, Vb, 768, 9);

    // width attention. O1 -> xb
    attn128<<<dim3(128, 12), 256, 0, stream>>>(Qb, Kb, Vb, xb, 128, 1);
    // height attention: V-input = O1 (xb). O2 -> Vb
    attn128<<<dim3(128, 12), 256, 0, stream>>>(Qb, Kb, xb, Vb, 1, 128);

    // output projection: M=16384, N=768, K=768, fp32 out. 64x3 = 192 blocks.
    gemm256<true><<<192, 512, 0, stream>>>(
        Vb, Wob, bo, bo, bo, out, out, out, 768, 3);
}